// Round 8
// baseline (147.627 us; speedup 1.0000x reference)
//
#include <hip/hip_runtime.h>
#include <math.h>

#define NB   4
#define NSEQ 8192
#define CDIM 64
#define M    2048
#define NW   7
#define NBLK2 40     // sub-blocks (QT,ci) per window: 4*1+4*2+4*3+4*4 (128-row q-tiles)

typedef _Float16 half8 __attribute__((ext_vector_type(8)));
typedef __fp16 fp16x2 __attribute__((ext_vector_type(2)));   // native cvt_pkrtz type
typedef float f32x4 __attribute__((ext_vector_type(4)));
typedef unsigned short u16x8 __attribute__((ext_vector_type(8)));

#if defined(__has_builtin) && __has_builtin(__builtin_amdgcn_exp2f)
#define EXP2(x) __builtin_amdgcn_exp2f(x)
#else
#define EXP2(x) __expf((x) * 0.69314718056f)
#endif

// Q pre-scale: 1/sqrt(64) * log2(e) folded into Qg so attn uses raw exp2
#define QSCALE 0.1803368801111204f
// exp bias: p = exp2(s' - PBIAS) keeps P under f16 max; scales P and l by
// 2^-PBIAS uniformly -> O invariant, constant lse shift cancels in mix.
#define PBIAS 4.0f

__device__ __forceinline__ int win_base(int w) {
    return (w < 4) ? (w << 11) : ((w < 6) ? ((w - 4) << 12) : 0);
}
__device__ __forceinline__ int win_stride(int w) {
    return (w < 4) ? 1 : ((w < 6) ? 2 : 4);
}

// ---------------- kernel 1: QKV projection, f16 outputs -------------------
// block = 64 (1 wave): lane owns output column; W columns live in registers
// (192 VGPRs -> needs the 512-VGPR budget of launch_bounds(64,1); capping
// lower forces catastrophic scratch spills - measured 377MB FETCH in R3).
__global__ __launch_bounds__(64, 1) void qkv_proj(
        const float* __restrict__ x,
        const float* __restrict__ Wq, const float* __restrict__ Wk,
        const float* __restrict__ Wv,
        _Float16* __restrict__ Qg, _Float16* __restrict__ Kg,
        _Float16* __restrict__ Vg) {
    __shared__ __align__(16) float xs[32][64];
    const int lane = threadIdx.x;
    const long rowbase = (long)blockIdx.x * 32;

    float wq[64], wk[64], wv[64];
#pragma unroll
    for (int i = 0; i < 64; ++i) {
        wq[i] = Wq[i * 64 + lane];
        wk[i] = Wk[i * 64 + lane];
        wv[i] = Wv[i * 64 + lane];
    }
#pragma unroll
    for (int i = 0; i < 8; ++i) {
        int idx = lane + i * 64;            // 512 float4 chunks: 32 rows x 16
        int r = idx >> 4, ch = idx & 15;
        *(float4*)&xs[r][ch * 4] = *(const float4*)&x[(rowbase + r) * 64 + ch * 4];
    }
    __syncthreads();
    for (int r = 0; r < 32; ++r) {
        float aq = 0.f, ak = 0.f, av = 0.f;
#pragma unroll
        for (int i = 0; i < 64; i += 4) {
            float4 xv = *(const float4*)&xs[r][i];
            aq += xv.x * wq[i] + xv.y * wq[i + 1] + xv.z * wq[i + 2] + xv.w * wq[i + 3];
            ak += xv.x * wk[i] + xv.y * wk[i + 1] + xv.z * wk[i + 2] + xv.w * wk[i + 3];
            av += xv.x * wv[i] + xv.y * wv[i + 1] + xv.z * wv[i + 2] + xv.w * wv[i + 3];
        }
        long o = (rowbase + r) * 64 + lane;
        Qg[o] = (_Float16)(aq * QSCALE);
        Kg[o] = (_Float16)ak;
        Vg[o] = (_Float16)av;
    }
}

// ---------------- kernel 2: split-K MFMA flash attention, 128-row q-tile --
// block = (b, w, QT, ci): q-tile 128 rows (wave owns strips wid and wid+4),
// k-steps of 64. K & Vt double-buffered LDS as R5/R7; K/Vt FRAGMENTS are
// read from LDS ONCE per step and reused for both strips (the LDS win).
// Strips share the wave-private Ps rows sequentially (same-wave DS order
// makes the write-after-read safe). 1 barrier/step.
__global__ __launch_bounds__(256, 3) void attn(
        const _Float16* __restrict__ Qg, const _Float16* __restrict__ Kg,
        const _Float16* __restrict__ Vg,
        _Float16* __restrict__ Op, float* __restrict__ LSEp) {
    __shared__ __align__(16) char smem[40960];
    // [0,16384): K dbuf (2x8KB); [16384,32768): Vt dbuf; [32768,40960): Ps 64x128B

    // decode (QT, ci) from blockIdx.x in [0,40)
    int id = blockIdx.x;
    int QT, ci;
    if (id < 4)       { QT = id;              ci = 0; }
    else if (id < 12) { int r = id - 4;  QT = 4  + (r >> 1); ci = r & 1; }
    else if (id < 24) { int r = id - 12; int q3 = r / 3; QT = 8 + q3; ci = r - 3 * q3; }
    else              { int r = id - 24; QT = 12 + (r >> 2); ci = r & 3; }
    const int w = blockIdx.y, b = blockIdx.z;
    const int base = win_base(w), stride = win_stride(w);
    const int g = QT >> 2;
    const int cb = 2 * g * (g + 1) + (QT & 3) * (g + 1);
    const int outblk = (b * NW + w) * NBLK2 + cb + ci;
    const int kt0 = ci * 8;
    const int ktmax = 2 * QT + 2;
    const int kt1 = (kt0 + 8 < ktmax) ? kt0 + 8 : ktmax;

    const _Float16* Qb = Qg + (size_t)b * NSEQ * 64;
    const _Float16* Kb = Kg + (size_t)b * NSEQ * 64;
    const _Float16* Vb = Vg + (size_t)b * NSEQ * 64;

    const int t = threadIdx.x;
    const int wid = t >> 6, lane = t & 63, l15 = lane & 15, quad = lane >> 4;

    // K staging map: thread stages rows sr0, sr0+32, 16B chunk sch each
    const int sr0 = t >> 3, sch = t & 7, sr1 = sr0 + 32;
    // V staging map: thread stages V rows (kpp, kpp+16), 8 d-columns
    const int kp = t & 31, d0 = (t >> 5) * 8;
    const int kpp = kp + ((kp >> 4) << 4);           // pairs (k,k+16), k in 0..15,32..47
    const int vu = (kp & 15) >> 1;
    const int vboff = ((kp & 1) * 8) + ((kp >> 4) * 4);

    // Q A-frags for both strips (strip0 rows 16wid+, strip1 rows 64+16wid+)
    const size_t qr0 = (size_t)(base + stride * (QT * 128 + 16 * wid + l15)) * 64;
    const size_t qr1 = (size_t)(base + stride * (QT * 128 + 64 + 16 * wid + l15)) * 64;
    const half8 qa00 = *(const half8*)(Qb + qr0 + quad * 8);
    const half8 qa01 = *(const half8*)(Qb + qr0 + 32 + quad * 8);
    const half8 qa10 = *(const half8*)(Qb + qr1 + quad * 8);
    const half8 qa11 = *(const half8*)(Qb + qr1 + 32 + quad * 8);

    f32x4 oacc0[4], oacc1[4];
    float l_[8];
#pragma unroll
    for (int ns = 0; ns < 4; ++ns) {
        oacc0[ns] = (f32x4){0.f, 0.f, 0.f, 0.f};
        oacc1[ns] = (f32x4){0.f, 0.f, 0.f, 0.f};
    }
#pragma unroll
    for (int j = 0; j < 8; ++j) l_[j] = 0.f;

    half8 pk0, pk1;
    u16x8 pv0, pv1;

    // ---- prologue: stage tile kt0 into buffer 0 ----
    {
        const size_t ka = (size_t)(base + stride * (kt0 * 64 + sr0)) * 64 + sch * 8;
        const size_t kb2 = (size_t)(base + stride * (kt0 * 64 + sr1)) * 64 + sch * 8;
        pk0 = *(const half8*)(Kb + ka);
        pk1 = *(const half8*)(Kb + kb2);
        const size_t va = (size_t)(base + stride * (kt0 * 64 + kpp)) * 64 + d0;
        pv0 = *(const u16x8*)(Vb + va);
        pv1 = *(const u16x8*)(Vb + va + (size_t)stride * 16 * 64);
        char* Kd = smem;
        char* Vd = smem + 16384;
        *(half8*)(Kd + sr0 * 128 + ((sch ^ (sr0 & 7)) * 16)) = pk0;
        *(half8*)(Kd + sr1 * 128 + ((sch ^ (sr1 & 7)) * 16)) = pk1;
#pragma unroll
        for (int i = 0; i < 8; ++i) {
            int d = d0 + i;
            unsigned int pkw = (unsigned int)pv0[i] | ((unsigned int)pv1[i] << 16);
            *(unsigned int*)(Vd + d * 128 + ((vu ^ (d & 7)) * 16) + vboff) = pkw;
        }
    }

    int cur = 0;
    for (int kt = kt0; kt < kt1; ++kt) {
        __syncthreads();   // buf[cur] visible; all reads of buf[cur^1] done
        const bool pf = (kt + 1 < kt1);
        if (pf) {   // prefetch next tile (consumed at end of this iteration)
            const size_t ka = (size_t)(base + stride * ((kt + 1) * 64 + sr0)) * 64 + sch * 8;
            const size_t kb2 = (size_t)(base + stride * ((kt + 1) * 64 + sr1)) * 64 + sch * 8;
            pk0 = *(const half8*)(Kb + ka);
            pk1 = *(const half8*)(Kb + kb2);
            const size_t va = (size_t)(base + stride * ((kt + 1) * 64 + kpp)) * 64 + d0;
            pv0 = *(const u16x8*)(Vb + va);
            pv1 = *(const u16x8*)(Vb + va + (size_t)stride * 16 * 64);
        }

        const char* Kd = smem + cur * 8192;
        const char* Vd = smem + 16384 + cur * 8192;
        char* PsB = smem + 32768;

        // ---- QK^T: K frags read ONCE, used by both strips ----
        f32x4 sa0[4], sa1[4];
#pragma unroll
        for (int ns = 0; ns < 4; ++ns) {
            const int krow = ns * 16 + l15, swk = krow & 7;
            half8 b0 = *(const half8*)(Kd + krow * 128 + ((quad ^ swk) * 16));
            half8 b1 = *(const half8*)(Kd + krow * 128 + (((quad + 4) ^ swk) * 16));
            f32x4 c0 = (f32x4){0.f, 0.f, 0.f, 0.f};
            c0 = __builtin_amdgcn_mfma_f32_16x16x32_f16(qa00, b0, c0, 0, 0, 0);
            c0 = __builtin_amdgcn_mfma_f32_16x16x32_f16(qa01, b1, c0, 0, 0, 0);
            sa0[ns] = c0;
            f32x4 c1 = (f32x4){0.f, 0.f, 0.f, 0.f};
            c1 = __builtin_amdgcn_mfma_f32_16x16x32_f16(qa10, b0, c1, 0, 0, 0);
            c1 = __builtin_amdgcn_mfma_f32_16x16x32_f16(qa11, b1, c1, 0, 0, 0);
            sa1[ns] = c1;
        }
        if (kt >= 2 * QT) {   // causal masking (diagonal spans 2 k-tiles)
            const int colb = (kt << 6) + l15;
            const int row0 = (QT << 7) + 16 * wid + (quad << 2);
#pragma unroll
            for (int ns = 0; ns < 4; ++ns)
#pragma unroll
                for (int j = 0; j < 4; ++j) {
                    if (colb + ns * 16 > row0 + j)      sa0[ns][j] = -1e30f;
                    if (colb + ns * 16 > row0 + 64 + j) sa1[ns][j] = -1e30f;
                }
        }

        // ---- Vt frags read ONCE, reused by both strips' PV ----
        half8 vb0[4], vb1[4];
#pragma unroll
        for (int ns = 0; ns < 4; ++ns) {
            const int d = ns * 16 + l15, swd = d & 7;
            vb0[ns] = *(const half8*)(Vd + d * 128 + ((quad ^ swd) * 16));
            vb1[ns] = *(const half8*)(Vd + d * 128 + (((quad + 4) ^ swd) * 16));
        }

        // ---- strip0: exp2 + P write + frag read + PV ----
#pragma unroll
        for (int j = 0; j < 4; ++j) {
            const int q = 16 * wid + quad * 4 + j;
            float p0 = EXP2(sa0[0][j] - PBIAS);
            float p1 = EXP2(sa0[1][j] - PBIAS);
            float p2 = EXP2(sa0[2][j] - PBIAS);
            float p3 = EXP2(sa0[3][j] - PBIAS);
            l_[j] += (p0 + p1) + (p2 + p3);
            union { fp16x2 h[2]; uint2 u; } pw;
            pw.h[0] = __builtin_amdgcn_cvt_pkrtz(p0, p1);
            pw.h[1] = __builtin_amdgcn_cvt_pkrtz(p2, p3);
            const int unit = (l15 >> 1) ^ ((q >> 2) & 7);
            *(uint2*)(PsB + q * 128 + unit * 16 + (l15 & 1) * 8) = pw.u;
        }
        {
            const int qp = 16 * wid + l15, swp = (qp >> 2) & 7;
            half8 pa0 = *(const half8*)(PsB + qp * 128 + ((quad ^ swp) * 16));
            half8 pa1 = *(const half8*)(PsB + qp * 128 + (((quad + 4) ^ swp) * 16));
#pragma unroll
            for (int ns = 0; ns < 4; ++ns) {
                oacc0[ns] = __builtin_amdgcn_mfma_f32_16x16x32_f16(pa0, vb0[ns], oacc0[ns], 0, 0, 0);
                oacc0[ns] = __builtin_amdgcn_mfma_f32_16x16x32_f16(pa1, vb1[ns], oacc0[ns], 0, 0, 0);
            }
        }

        // ---- strip1: same Ps rows (same-wave DS ordering => safe) ----
#pragma unroll
        for (int j = 0; j < 4; ++j) {
            const int q = 16 * wid + quad * 4 + j;
            float p0 = EXP2(sa1[0][j] - PBIAS);
            float p1 = EXP2(sa1[1][j] - PBIAS);
            float p2 = EXP2(sa1[2][j] - PBIAS);
            float p3 = EXP2(sa1[3][j] - PBIAS);
            l_[4 + j] += (p0 + p1) + (p2 + p3);
            union { fp16x2 h[2]; uint2 u; } pw;
            pw.h[0] = __builtin_amdgcn_cvt_pkrtz(p0, p1);
            pw.h[1] = __builtin_amdgcn_cvt_pkrtz(p2, p3);
            const int unit = (l15 >> 1) ^ ((q >> 2) & 7);
            *(uint2*)(PsB + q * 128 + unit * 16 + (l15 & 1) * 8) = pw.u;
        }
        {
            const int qp = 16 * wid + l15, swp = (qp >> 2) & 7;
            half8 pa0 = *(const half8*)(PsB + qp * 128 + ((quad ^ swp) * 16));
            half8 pa1 = *(const half8*)(PsB + qp * 128 + (((quad + 4) ^ swp) * 16));
#pragma unroll
            for (int ns = 0; ns < 4; ++ns) {
                oacc1[ns] = __builtin_amdgcn_mfma_f32_16x16x32_f16(pa0, vb0[ns], oacc1[ns], 0, 0, 0);
                oacc1[ns] = __builtin_amdgcn_mfma_f32_16x16x32_f16(pa1, vb1[ns], oacc1[ns], 0, 0, 0);
            }
        }

        // ---- write prefetched tile into the other buffer ----
        if (pf) {
            char* Kn = smem + (cur ^ 1) * 8192;
            char* Vn = smem + 16384 + (cur ^ 1) * 8192;
            *(half8*)(Kn + sr0 * 128 + ((sch ^ (sr0 & 7)) * 16)) = pk0;
            *(half8*)(Kn + sr1 * 128 + ((sch ^ (sr1 & 7)) * 16)) = pk1;
#pragma unroll
            for (int i = 0; i < 8; ++i) {
                int d = d0 + i;
                unsigned int pkw = (unsigned int)pv0[i] | ((unsigned int)pv1[i] << 16);
                *(unsigned int*)(Vn + d * 128 + ((vu ^ (d & 7)) * 16) + vboff) = pkw;
            }
        }
        cur ^= 1;
    }

    // ---- epilogue: reduce l, store O (f16) and lse per strip ----
#pragma unroll
    for (int j = 0; j < 8; ++j) {
        float s = l_[j];
        s += __shfl_xor(s, 1, 16);
        s += __shfl_xor(s, 2, 16);
        s += __shfl_xor(s, 4, 16);
        s += __shfl_xor(s, 8, 16);
        l_[j] = s;
    }
    const int qrow0 = 16 * wid + quad * 4;
    if (l15 == 0) {
#pragma unroll
        for (int j = 0; j < 4; ++j) {
            LSEp[(size_t)outblk * 128 + qrow0 + j]      = __logf(l_[j]);
            LSEp[(size_t)outblk * 128 + 64 + qrow0 + j] = __logf(l_[4 + j]);
        }
    }
#pragma unroll
    for (int j = 0; j < 4; ++j) {
        const float inv0 = 1.0f / l_[j];
        const float inv1 = 1.0f / l_[4 + j];
        const size_t r0off = ((size_t)outblk * 128 + qrow0 + j) * 64 + l15;
        const size_t r1off = ((size_t)outblk * 128 + 64 + qrow0 + j) * 64 + l15;
#pragma unroll
        for (int ns = 0; ns < 4; ++ns) {
            Op[r0off + ns * 16] = (_Float16)(oacc0[ns][j] * inv0);
            Op[r1off + ns * 16] = (_Float16)(oacc1[ns][j] * inv1);
        }
    }
}

// ---------------- kernel 3: merge all (window, chunk) partials ------------
__global__ __launch_bounds__(256) void mix_out(
        const _Float16* __restrict__ Op, const float* __restrict__ LSEp,
        float* __restrict__ out) {
    int gid = blockIdx.x * 256 + threadIdx.x;   // [0, 4*8192*8)
    int f8 = gid & 7;
    int tpos = (gid >> 3) & (NSEQ - 1);
    int b = gid >> 16;

    int idxs[12];
    float lse[12];
    int nref = 0;
    {   // window of stride 1
        int w = tpos >> 11, j = tpos & (M - 1);
        int QT = j >> 7, gg = QT >> 2, q = j & 127;
        int cbase = 2 * gg * (gg + 1) + (QT & 3) * (gg + 1);
        int bb = ((b * NW + w) * NBLK2 + cbase) * 128 + q;
        int cmax = j >> 9;
        for (int c = 0; c <= cmax; ++c) { idxs[nref] = bb + c * 128; lse[nref] = LSEp[idxs[nref]]; ++nref; }
    }
    if (!(tpos & 1)) {   // stride 2
        int w = 4 + (tpos >> 12), j = (tpos & 4095) >> 1;
        int QT = j >> 7, gg = QT >> 2, q = j & 127;
        int cbase = 2 * gg * (gg + 1) + (QT & 3) * (gg + 1);
        int bb = ((b * NW + w) * NBLK2 + cbase) * 128 + q;
        int cmax = j >> 9;
        for (int c = 0; c <= cmax; ++c) { idxs[nref] = bb + c * 128; lse[nref] = LSEp[idxs[nref]]; ++nref; }
    }
    if (!(tpos & 3)) {   // stride 4
        int j = tpos >> 2;
        int QT = j >> 7, gg = QT >> 2, q = j & 127;
        int cbase = 2 * gg * (gg + 1) + (QT & 3) * (gg + 1);
        int bb = ((b * NW + 6) * NBLK2 + cbase) * 128 + q;
        int cmax = j >> 9;
        for (int c = 0; c <= cmax; ++c) { idxs[nref] = bb + c * 128; lse[nref] = LSEp[idxs[nref]]; ++nref; }
    }

    float Mx = -1e30f;
    for (int i = 0; i < nref; ++i) Mx = fmaxf(Mx, lse[i]);
    float acc[8];
#pragma unroll
    for (int k = 0; k < 8; ++k) acc[k] = 0.f;
    float wsum = 0.f;
    for (int i = 0; i < nref; ++i) {
        float a = __expf(lse[i] - Mx);
        wsum += a;
        half8 v = *(const half8*)(Op + (size_t)idxs[i] * 64 + f8 * 8);
#pragma unroll
        for (int k = 0; k < 8; ++k) acc[k] += a * (float)v[k];
    }
    float inv = 1.0f / wsum;
    size_t o = ((size_t)b * NSEQ + tpos) * 64 + f8 * 8;
    float4 r0 = make_float4(acc[0] * inv, acc[1] * inv, acc[2] * inv, acc[3] * inv);
    float4 r1 = make_float4(acc[4] * inv, acc[5] * inv, acc[6] * inv, acc[7] * inv);
    *(float4*)&out[o] = r0;
    *(float4*)&out[o + 4] = r1;
}

extern "C" void kernel_launch(void* const* d_in, const int* in_sizes, int n_in,
                              void* d_out, int out_size, void* d_ws, size_t ws_size,
                              hipStream_t stream) {
    const float* x  = (const float*)d_in[0];
    const float* Wq = (const float*)d_in[1];
    const float* Wk = (const float*)d_in[2];
    const float* Wv = (const float*)d_in[3];
    float* out = (float*)d_out;

    const size_t QN = (size_t)NB * NSEQ * CDIM;     // 2,097,152
    _Float16* Qg = (_Float16*)d_ws;
    _Float16* Kg = Qg + QN;
    _Float16* Vg = Kg + QN;
    _Float16* Op = Vg + QN;                         // [b][w][40][128][64] f16
    float* LSEp  = (float*)(Op + (size_t)NB * NW * NBLK2 * 128 * 64);

    qkv_proj<<<NB * NSEQ / 32, 64, 0, stream>>>(x, Wq, Wk, Wv, Qg, Kg, Vg);
    attn<<<dim3(NBLK2, NW, NB), 256, 0, stream>>>(Qg, Kg, Vg, Op, LSEp);
    mix_out<<<(NB * NSEQ * 8) / 256, 256, 0, stream>>>(Op, LSEp, out);
}

// Round 9
// 144.221 us; speedup vs baseline: 1.0236x; 1.0236x over previous
//
#include <hip/hip_runtime.h>
#include <math.h>

#define NB   4
#define NSEQ 8192
#define CDIM 64
#define M    2048
#define NW   7
#define NBLK 80      // sub-blocks (qt,ci) per window: 8*1+8*2+8*3+8*4

typedef _Float16 half8 __attribute__((ext_vector_type(8)));
typedef __fp16 fp16x2 __attribute__((ext_vector_type(2)));   // native cvt_pkrtz type
typedef float f32x4 __attribute__((ext_vector_type(4)));
typedef unsigned short u16x8 __attribute__((ext_vector_type(8)));

#if defined(__has_builtin) && __has_builtin(__builtin_amdgcn_exp2f)
#define EXP2(x) __builtin_amdgcn_exp2f(x)
#else
#define EXP2(x) __expf((x) * 0.69314718056f)
#endif

// Q pre-scale: 1/sqrt(64) * log2(e) folded into Qg so attn uses raw exp2
#define QSCALE 0.1803368801111204f
// exp bias: p = exp2(s' - PBIAS) keeps P under f16 max; scales P and l by
// 2^-PBIAS uniformly -> O invariant, constant lse shift cancels in mix.
#define PBIAS 4.0f

__device__ __forceinline__ int win_base(int w) {
    return (w < 4) ? (w << 11) : ((w < 6) ? ((w - 4) << 12) : 0);
}
__device__ __forceinline__ int win_stride(int w) {
    return (w < 4) ? 1 : ((w < 6) ? 2 : 4);
}

// ---------------- kernel 1: QKV projection, f16 outputs -------------------
// block = 64 (1 wave): lane owns output column; W columns live in registers
// (192 VGPRs -> needs the 512-VGPR budget of launch_bounds(64,1); capping
// lower forces catastrophic scratch spills - measured 377MB FETCH in R3).
__global__ __launch_bounds__(64, 1) void qkv_proj(
        const float* __restrict__ x,
        const float* __restrict__ Wq, const float* __restrict__ Wk,
        const float* __restrict__ Wv,
        _Float16* __restrict__ Qg, _Float16* __restrict__ Kg,
        _Float16* __restrict__ Vg) {
    __shared__ __align__(16) float xs[32][64];
    const int lane = threadIdx.x;
    const long rowbase = (long)blockIdx.x * 32;

    float wq[64], wk[64], wv[64];
#pragma unroll
    for (int i = 0; i < 64; ++i) {
        wq[i] = Wq[i * 64 + lane];
        wk[i] = Wk[i * 64 + lane];
        wv[i] = Wv[i * 64 + lane];
    }
#pragma unroll
    for (int i = 0; i < 8; ++i) {
        int idx = lane + i * 64;            // 512 float4 chunks: 32 rows x 16
        int r = idx >> 4, ch = idx & 15;
        *(float4*)&xs[r][ch * 4] = *(const float4*)&x[(rowbase + r) * 64 + ch * 4];
    }
    __syncthreads();
    for (int r = 0; r < 32; ++r) {
        float aq = 0.f, ak = 0.f, av = 0.f;
#pragma unroll
        for (int i = 0; i < 64; i += 4) {
            float4 xv = *(const float4*)&xs[r][i];
            aq += xv.x * wq[i] + xv.y * wq[i + 1] + xv.z * wq[i + 2] + xv.w * wq[i + 3];
            ak += xv.x * wk[i] + xv.y * wk[i + 1] + xv.z * wk[i + 2] + xv.w * wk[i + 3];
            av += xv.x * wv[i] + xv.y * wv[i + 1] + xv.z * wv[i + 2] + xv.w * wv[i + 3];
        }
        long o = (rowbase + r) * 64 + lane;
        Qg[o] = (_Float16)(aq * QSCALE);
        Kg[o] = (_Float16)ak;
        Vg[o] = (_Float16)av;
    }
}

// ---------------- kernel 2: split-K MFMA flash attention ------------------
// block = (b, w, qt, ci). K & Vt double-buffered in LDS (coalesced staging,
// prefetch issued after the barrier, consumed after compute). Wave-private P
// under k-permutation pi(k)=4*(k&15)+(k>>4) -> P round-trip = 4x ds_write_b64.
// 1 barrier/step. HEAVY-FIRST dispatch: id = 79-blockIdx.x so 8-step chunks
// launch first and 1-step chunks drain the tail (R8 lesson: latency-bound,
// tail packing > per-step traffic).
__global__ __launch_bounds__(256, 4) void attn(
        const _Float16* __restrict__ Qg, const _Float16* __restrict__ Kg,
        const _Float16* __restrict__ Vg,
        _Float16* __restrict__ Op, float* __restrict__ LSEp) {
    __shared__ __align__(16) char smem[40960];
    // [0,16384): K dbuf (2x8KB); [16384,32768): Vt dbuf; [32768,40960): Ps

    // decode (qt, ci) from reversed blockIdx.x in [0,80): heavy groups first
    int id = 79 - (int)blockIdx.x;
    int qt, ci;
    if (id < 8)       { qt = id;               ci = 0; }
    else if (id < 24) { int r = id - 8;  qt = 8  + (r >> 1); ci = r & 1; }
    else if (id < 48) { int r = id - 24; int q3 = r / 3; qt = 16 + q3; ci = r - 3 * q3; }
    else              { int r = id - 48; qt = 24 + (r >> 2); ci = r & 3; }
    const int w = blockIdx.y, b = blockIdx.z;
    const int base = win_base(w), stride = win_stride(w);
    const int g = qt >> 3;
    const int outblk = (b * NW + w) * NBLK + (g + 1) * (4 * g + (qt & 7)) + ci;
    const int kt0 = ci * 8;
    const int kt1 = (kt0 + 8 < qt + 1) ? kt0 + 8 : qt + 1;

    const _Float16* Qb = Qg + (size_t)b * NSEQ * 64;
    const _Float16* Kb = Kg + (size_t)b * NSEQ * 64;
    const _Float16* Vb = Vg + (size_t)b * NSEQ * 64;

    const int t = threadIdx.x;
    const int wid = t >> 6, lane = t & 63, l15 = lane & 15, quad = lane >> 4;

    // K staging map: thread stages rows sr0, sr0+32, 16B chunk sch each
    const int sr0 = t >> 3, sch = t & 7, sr1 = sr0 + 32;
    // V staging map: thread stages V rows (kpp, kpp+16), 8 d-columns
    const int kp = t & 31, d0 = (t >> 5) * 8;
    const int kpp = kp + ((kp >> 4) << 4);           // 0..15 -> 0..15; 16..31 -> 32..47
    const int vu = (kp & 15) >> 1;                   // 16B unit in Vt row
    const int vboff = ((kp & 1) * 8) + ((kp >> 4) * 4);

    // Q A-frags: load once (A[m=l15][k=quad*8+j])
    const size_t qr = (size_t)(base + stride * (qt * 64 + 16 * wid + l15)) * 64;
    const half8 qa0 = *(const half8*)(Qb + qr + quad * 8);
    const half8 qa1 = *(const half8*)(Qb + qr + 32 + quad * 8);

    f32x4 oacc[4];
    float l_[4];
#pragma unroll
    for (int ns = 0; ns < 4; ++ns) oacc[ns] = (f32x4){0.f, 0.f, 0.f, 0.f};
#pragma unroll
    for (int j = 0; j < 4; ++j) l_[j] = 0.f;

    half8 pk0, pk1;
    u16x8 pv0, pv1;

    // ---- prologue: stage tile kt0 into buffer 0 ----
    {
        const size_t ka = (size_t)(base + stride * (kt0 * 64 + sr0)) * 64 + sch * 8;
        const size_t kb2 = (size_t)(base + stride * (kt0 * 64 + sr1)) * 64 + sch * 8;
        pk0 = *(const half8*)(Kb + ka);
        pk1 = *(const half8*)(Kb + kb2);
        const size_t va = (size_t)(base + stride * (kt0 * 64 + kpp)) * 64 + d0;
        pv0 = *(const u16x8*)(Vb + va);
        pv1 = *(const u16x8*)(Vb + va + (size_t)stride * 16 * 64);
        char* Kd = smem;
        char* Vd = smem + 16384;
        *(half8*)(Kd + sr0 * 128 + ((sch ^ (sr0 & 7)) * 16)) = pk0;
        *(half8*)(Kd + sr1 * 128 + ((sch ^ (sr1 & 7)) * 16)) = pk1;
#pragma unroll
        for (int i = 0; i < 8; ++i) {
            int d = d0 + i;
            unsigned int pkw = (unsigned int)pv0[i] | ((unsigned int)pv1[i] << 16);
            *(unsigned int*)(Vd + d * 128 + ((vu ^ (d & 7)) * 16) + vboff) = pkw;
        }
    }

    int cur = 0;
    for (int kt = kt0; kt < kt1; ++kt) {
        __syncthreads();   // buf[cur] visible; all reads of buf[cur^1] done
        const bool pf = (kt + 1 < kt1);
        if (pf) {   // prefetch next tile (consumed at end of this iteration)
            const size_t ka = (size_t)(base + stride * ((kt + 1) * 64 + sr0)) * 64 + sch * 8;
            const size_t kb2 = (size_t)(base + stride * ((kt + 1) * 64 + sr1)) * 64 + sch * 8;
            pk0 = *(const half8*)(Kb + ka);
            pk1 = *(const half8*)(Kb + kb2);
            const size_t va = (size_t)(base + stride * ((kt + 1) * 64 + kpp)) * 64 + d0;
            pv0 = *(const u16x8*)(Vb + va);
            pv1 = *(const u16x8*)(Vb + va + (size_t)stride * 16 * 64);
        }

        const char* Kd = smem + cur * 8192;
        const char* Vd = smem + 16384 + cur * 8192;
        char* PsB = smem + 32768;

        // ---- QK^T from LDS K + register Q frags ----
        f32x4 sa[4];
#pragma unroll
        for (int ns = 0; ns < 4; ++ns) {
            const int krow = ns * 16 + l15, swk = krow & 7;
            half8 b0 = *(const half8*)(Kd + krow * 128 + ((quad ^ swk) * 16));
            half8 b1 = *(const half8*)(Kd + krow * 128 + (((quad + 4) ^ swk) * 16));
            f32x4 c = (f32x4){0.f, 0.f, 0.f, 0.f};
            c = __builtin_amdgcn_mfma_f32_16x16x32_f16(qa0, b0, c, 0, 0, 0);
            c = __builtin_amdgcn_mfma_f32_16x16x32_f16(qa1, b1, c, 0, 0, 0);
            sa[ns] = c;
        }
        if (kt == qt) {   // causal mask inside diagonal tile
#pragma unroll
            for (int ns = 0; ns < 4; ++ns)
#pragma unroll
                for (int j = 0; j < 4; ++j)
                    if (ns * 16 + l15 > 16 * wid + quad * 4 + j) sa[ns][j] = -1e30f;
        }

        // ---- exp2, l accum, P write (pi-permuted cols -> one b64 per j) ----
#pragma unroll
        for (int j = 0; j < 4; ++j) {
            const int q = 16 * wid + quad * 4 + j;
            float p0 = EXP2(sa[0][j] - PBIAS);
            float p1 = EXP2(sa[1][j] - PBIAS);
            float p2 = EXP2(sa[2][j] - PBIAS);
            float p3 = EXP2(sa[3][j] - PBIAS);
            l_[j] += (p0 + p1) + (p2 + p3);
            union { fp16x2 h[2]; uint2 u; } pw;
            pw.h[0] = __builtin_amdgcn_cvt_pkrtz(p0, p1);
            pw.h[1] = __builtin_amdgcn_cvt_pkrtz(p2, p3);
            const int unit = (l15 >> 1) ^ ((q >> 2) & 7);
            *(uint2*)(PsB + q * 128 + unit * 16 + (l15 & 1) * 8) = pw.u;
        }

        // own-strip P A-frags (wave-private: no barrier needed)
        const int qp = 16 * wid + l15, swp = (qp >> 2) & 7;
        half8 pa0 = *(const half8*)(PsB + qp * 128 + ((quad ^ swp) * 16));
        half8 pa1 = *(const half8*)(PsB + qp * 128 + (((quad + 4) ^ swp) * 16));

        // ---- PV: O[q][d] += P(A) * Vt(B), both in pi(k) order ----
#pragma unroll
        for (int ns = 0; ns < 4; ++ns) {
            const int d = ns * 16 + l15, swd = d & 7;
            half8 vb0 = *(const half8*)(Vd + d * 128 + ((quad ^ swd) * 16));
            half8 vb1 = *(const half8*)(Vd + d * 128 + (((quad + 4) ^ swd) * 16));
            oacc[ns] = __builtin_amdgcn_mfma_f32_16x16x32_f16(pa0, vb0, oacc[ns], 0, 0, 0);
            oacc[ns] = __builtin_amdgcn_mfma_f32_16x16x32_f16(pa1, vb1, oacc[ns], 0, 0, 0);
        }

        // ---- write prefetched tile into the other buffer ----
        if (pf) {
            char* Kn = smem + (cur ^ 1) * 8192;
            char* Vn = smem + 16384 + (cur ^ 1) * 8192;
            *(half8*)(Kn + sr0 * 128 + ((sch ^ (sr0 & 7)) * 16)) = pk0;
            *(half8*)(Kn + sr1 * 128 + ((sch ^ (sr1 & 7)) * 16)) = pk1;
#pragma unroll
            for (int i = 0; i < 8; ++i) {
                int d = d0 + i;
                unsigned int pkw = (unsigned int)pv0[i] | ((unsigned int)pv1[i] << 16);
                *(unsigned int*)(Vn + d * 128 + ((vu ^ (d & 7)) * 16) + vboff) = pkw;
            }
        }
        cur ^= 1;
    }

    // ---- epilogue: reduce l over the 16 lanes of each quad-row, store ----
#pragma unroll
    for (int j = 0; j < 4; ++j) {
        float s = l_[j];
        s += __shfl_xor(s, 1, 16);
        s += __shfl_xor(s, 2, 16);
        s += __shfl_xor(s, 4, 16);
        s += __shfl_xor(s, 8, 16);
        l_[j] = s;
    }
    const int qrow = 16 * wid + quad * 4;
    if (l15 == 0) {
#pragma unroll
        for (int j = 0; j < 4; ++j)
            LSEp[(size_t)outblk * 64 + qrow + j] = __logf(l_[j]);
    }
#pragma unroll
    for (int j = 0; j < 4; ++j) {
        const float inv = 1.0f / l_[j];
        const size_t rowoff = ((size_t)outblk * 64 + qrow + j) * 64 + l15;
#pragma unroll
        for (int ns = 0; ns < 4; ++ns)
            Op[rowoff + ns * 16] = (_Float16)(oacc[ns][j] * inv);
    }
}

// ---------------- kernel 3: merge all (window, chunk) partials ------------
__global__ __launch_bounds__(256) void mix_out(
        const _Float16* __restrict__ Op, const float* __restrict__ LSEp,
        float* __restrict__ out) {
    int gid = blockIdx.x * 256 + threadIdx.x;   // [0, 4*8192*8)
    int f8 = gid & 7;
    int tpos = (gid >> 3) & (NSEQ - 1);
    int b = gid >> 16;

    int idxs[12];
    float lse[12];
    int nref = 0;
    {   // window of stride 1
        int w = tpos >> 11, j = tpos & (M - 1);
        int qt = j >> 6, gg = qt >> 3, q = j & 63;
        int bb = ((b * NW + w) * NBLK + (gg + 1) * (4 * gg + (qt & 7))) * 64 + q;
        for (int c = 0; c <= gg; ++c) { idxs[nref] = bb + c * 64; lse[nref] = LSEp[idxs[nref]]; ++nref; }
    }
    if (!(tpos & 1)) {   // stride 2
        int w = 4 + (tpos >> 12), j = (tpos & 4095) >> 1;
        int qt = j >> 6, gg = qt >> 3, q = j & 63;
        int bb = ((b * NW + w) * NBLK + (gg + 1) * (4 * gg + (qt & 7))) * 64 + q;
        for (int c = 0; c <= gg; ++c) { idxs[nref] = bb + c * 64; lse[nref] = LSEp[idxs[nref]]; ++nref; }
    }
    if (!(tpos & 3)) {   // stride 4
        int j = tpos >> 2;
        int qt = j >> 6, gg = qt >> 3, q = j & 63;
        int bb = ((b * NW + 6) * NBLK + (gg + 1) * (4 * gg + (qt & 7))) * 64 + q;
        for (int c = 0; c <= gg; ++c) { idxs[nref] = bb + c * 64; lse[nref] = LSEp[idxs[nref]]; ++nref; }
    }

    float Mx = -1e30f;
    for (int i = 0; i < nref; ++i) Mx = fmaxf(Mx, lse[i]);
    float acc[8];
#pragma unroll
    for (int k = 0; k < 8; ++k) acc[k] = 0.f;
    float wsum = 0.f;
    for (int i = 0; i < nref; ++i) {
        float a = __expf(lse[i] - Mx);
        wsum += a;
        half8 v = *(const half8*)(Op + (size_t)idxs[i] * 64 + f8 * 8);
#pragma unroll
        for (int k = 0; k < 8; ++k) acc[k] += a * (float)v[k];
    }
    float inv = 1.0f / wsum;
    size_t o = ((size_t)b * NSEQ + tpos) * 64 + f8 * 8;
    float4 r0 = make_float4(acc[0] * inv, acc[1] * inv, acc[2] * inv, acc[3] * inv);
    float4 r1 = make_float4(acc[4] * inv, acc[5] * inv, acc[6] * inv, acc[7] * inv);
    *(float4*)&out[o] = r0;
    *(float4*)&out[o + 4] = r1;
}

extern "C" void kernel_launch(void* const* d_in, const int* in_sizes, int n_in,
                              void* d_out, int out_size, void* d_ws, size_t ws_size,
                              hipStream_t stream) {
    const float* x  = (const float*)d_in[0];
    const float* Wq = (const float*)d_in[1];
    const float* Wk = (const float*)d_in[2];
    const float* Wv = (const float*)d_in[3];
    float* out = (float*)d_out;

    const size_t QN = (size_t)NB * NSEQ * CDIM;     // 2,097,152
    _Float16* Qg = (_Float16*)d_ws;
    _Float16* Kg = Qg + QN;
    _Float16* Vg = Kg + QN;
    _Float16* Op = Vg + QN;                         // [b][w][80][64][64] f16
    float* LSEp  = (float*)(Op + (size_t)NB * NW * NBLK * 64 * 64);

    qkv_proj<<<NB * NSEQ / 32, 64, 0, stream>>>(x, Wq, Wk, Wv, Qg, Kg, Vg);
    attn<<<dim3(NBLK, NW, NB), 256, 0, stream>>>(Qg, Kg, Vg, Op, LSEp);
    mix_out<<<(NB * NSEQ * 8) / 256, 256, 0, stream>>>(Op, LSEp, out);
}